// Round 5
// baseline (1188.487 us; speedup 1.0000x reference)
//
#include <hip/hip_runtime.h>
#include <math.h>
#include <stdint.h>

// Fused LSTM via 3-term bf16-compensated MFMA, v4: K-split for occupancy.
// B=1024, S=1024, H=128, gates 4H=512.
// 256 blocks x 1024 threads (16 waves = 4 waves/SIMD; MFMA blocks its wave,
// so wave count per SIMD is the MFMA-throughput lever).
// Waves 0-7 (hf=0) compute K[0:64), waves 8-15 (hf=1) K[64:128) partials of
// gates = h @ Wh. hf1 writes float4 partials to LDS; hf0 combines, applies
// activations, updates c,h and writes h (bf16 hi/lo) to the A double-buffer.
// Real batch rows at tile rows {0,4,8,12}: acc[g][0] = own (elem q, unit u).

constexpr int Bsz = 1024;
constexpr int Ssz = 1024;
constexpr int Hh  = 128;
constexpr int NT  = 1024;
constexpr int EPB = 4;

using short8 = __attribute__((ext_vector_type(8))) short;
using f32x4  = __attribute__((ext_vector_type(4))) float;

__device__ __forceinline__ uint16_t bf_rne(float v) {
    uint32_t u = __float_as_uint(v);
    u += 0x7FFFu + ((u >> 16) & 1u);
    return (uint16_t)(u >> 16);
}
__device__ __forceinline__ float bf2f(uint16_t s) {
    return __uint_as_float(((uint32_t)s) << 16);
}
__device__ __forceinline__ float sigm(float x) {
    return __builtin_amdgcn_rcpf(1.0f + __expf(-x));
}
__device__ __forceinline__ float tanh_fast(float x) {
    return 1.0f - 2.0f * __builtin_amdgcn_rcpf(1.0f + __expf(2.0f * x));
}

// Logical byte offset of k within a 256 B A-row (fragment-contiguous layout):
// lane group q reading ktile kt finds its short8 at logical kt*64 + q*16.
__device__ __forceinline__ int kbyte_of_u(int k) {
    return ((k >> 5) << 6) + (((k & 15) >> 2) << 4) + (((k & 3) + ((k >> 4) & 1) * 4) << 1);
}

__global__ __launch_bounds__(NT, 4)
void lstm_mfma4(const float* __restrict__ x,  const float* __restrict__ Wi,
                const float* __restrict__ Wh, const float* __restrict__ bias,
                const float* __restrict__ Wd, const float* __restrict__ bd,
                float* __restrict__ out)
{
    __shared__ float xs[Ssz][EPB];                       // 16 KB x transposed
    __shared__ __align__(16) uint16_t Ahi[2][16 * Hh];   // 2x4 KB h hi, dbuf
    __shared__ __align__(16) uint16_t Alo[2][16 * Hh];   // 2x4 KB h lo, dbuf
    __shared__ __align__(16) float4 part[EPB][Hh];       // 8 KB K-half partials
    __shared__ float red[512];                           // 2 KB epilogue

    const int t  = threadIdx.x;
    const int w  = t >> 6;                 // wave 0..15
    const int hf = w >> 3;                 // K-half: 0 -> k<64, 1 -> k>=64
    const int W  = w & 7;                  // unit-group
    const int l  = t & 63;
    const int q  = l >> 4;                 // elem (C tile row 4q)
    const int cl = l & 15;
    const int b0 = blockIdx.x * EPB;
    const int u  = 16 * W + cl;            // this lane's hidden unit

    // stage x transposed (coalesced, one-time)
    for (int i = t; i < EPB * Ssz; i += NT) {
        int e = i >> 10, s = i & (Ssz - 1);
        xs[s][e] = x[(size_t)(b0 + e) * Ssz + s];
    }
    // zero A buffers (rows != {0,4,8,12} stay zero forever)
    {
        uint32_t* pa = (uint32_t*)Ahi;
        uint32_t* pb = (uint32_t*)Alo;
        for (int i = t; i < 2048; i += NT) { pa[i] = 0u; pb[i] = 0u; }
    }

    // B fragments for THIS K-half: 4 gates x 2 ktiles, bf16 hi/lo
    short8 Bhi[4][2], Blo[4][2];
    #pragma unroll
    for (int g = 0; g < 4; ++g) {
        const int colabs = g * Hh + u;
        #pragma unroll
        for (int kt = 0; kt < 2; ++kt) {
            #pragma unroll
            for (int j = 0; j < 8; ++j) {
                int k = (2 * hf + kt) * 32 + ((j >> 2) << 4) + q * 4 + (j & 3);
                float v = Wh[k * 512 + colabs];
                uint16_t hi = bf_rne(v);
                uint16_t lo = bf_rne(v - bf2f(hi));
                Bhi[g][kt][j] = (short)hi;
                Blo[g][kt][j] = (short)lo;
            }
        }
    }
    float wi_g[4], b_g[4];
    #pragma unroll
    for (int g = 0; g < 4; ++g) {
        wi_g[g] = Wi[g * Hh + u];
        b_g[g]  = bias[g * Hh + u];
    }

    // A-frag read offsets (row cl, this K-half; phase-rotated, conflict-free)
    int roff[2];
    #pragma unroll
    for (int kt = 0; kt < 2; ++kt)
        roff[kt] = cl * 256 + (((2 * hf + kt) * 64 + q * 16 + cl * 16) & 255);
    const bool aload = ((cl & 3) == 0);
    const int woff = (q * 4) * 256 + ((kbyte_of_u(u) + q * 64) & 255);

    short8 ah[2], al[2];
    #pragma unroll
    for (int kt = 0; kt < 2; ++kt) {
        ah[kt] = (short8){0,0,0,0,0,0,0,0};
        al[kt] = (short8){0,0,0,0,0,0,0,0};
    }
    const f32x4 zv = (f32x4){0.f, 0.f, 0.f, 0.f};

    float cst = 0.f, h_st = 0.f;
    __syncthreads();

    for (int s = 0; s < Ssz; ++s) {
        const char* Ah = (const char*)&Ahi[s & 1][0];
        const char* Al = (const char*)&Alo[s & 1][0];
        if (aload) {
            #pragma unroll
            for (int kt = 0; kt < 2; ++kt) {
                ah[kt] = *(const short8*)(Ah + roff[kt]);
                al[kt] = *(const short8*)(Al + roff[kt]);
            }
        }
        // 6-deep chain per gate, 4 independent chains (dep distance 4)
        f32x4 ca[4];
        #pragma unroll
        for (int g = 0; g < 4; ++g)
            ca[g] = __builtin_amdgcn_mfma_f32_16x16x32_bf16(ah[0], Bhi[g][0], zv, 0, 0, 0);
        #pragma unroll
        for (int g = 0; g < 4; ++g)
            ca[g] = __builtin_amdgcn_mfma_f32_16x16x32_bf16(ah[1], Bhi[g][1], ca[g], 0, 0, 0);
        #pragma unroll
        for (int g = 0; g < 4; ++g)
            ca[g] = __builtin_amdgcn_mfma_f32_16x16x32_bf16(al[0], Bhi[g][0], ca[g], 0, 0, 0);
        #pragma unroll
        for (int g = 0; g < 4; ++g)
            ca[g] = __builtin_amdgcn_mfma_f32_16x16x32_bf16(al[1], Bhi[g][1], ca[g], 0, 0, 0);
        #pragma unroll
        for (int g = 0; g < 4; ++g)
            ca[g] = __builtin_amdgcn_mfma_f32_16x16x32_bf16(ah[0], Blo[g][0], ca[g], 0, 0, 0);
        #pragma unroll
        for (int g = 0; g < 4; ++g)
            ca[g] = __builtin_amdgcn_mfma_f32_16x16x32_bf16(ah[1], Blo[g][1], ca[g], 0, 0, 0);

        if (hf == 1) {
            part[q][u] = make_float4(ca[0][0], ca[1][0], ca[2][0], ca[3][0]);
        }
        __syncthreads();   // partials ready

        if (hf == 0) {
            const float4 pp = part[q][u];
            const float xv = xs[s][q];
            float pi = (ca[0][0] + pp.x) + fmaf(xv, wi_g[0], b_g[0]);
            float pf = (ca[1][0] + pp.y) + fmaf(xv, wi_g[1], b_g[1]);
            float pg = (ca[2][0] + pp.z) + fmaf(xv, wi_g[2], b_g[2]);
            float po = (ca[3][0] + pp.w) + fmaf(xv, wi_g[3], b_g[3]);
            float ig = sigm(pi);
            float fg = sigm(pf);
            float gg = tanh_fast(pg);
            float og = sigm(po);
            cst  = fmaf(fg, cst, ig * gg);
            h_st = og * tanh_fast(cst);
            uint16_t hi = bf_rne(h_st);
            uint16_t lo = bf_rne(h_st - bf2f(hi));
            *(uint16_t*)((char*)&Ahi[(s + 1) & 1][0] + woff) = hi;
            *(uint16_t*)((char*)&Alo[(s + 1) & 1][0] + woff) = lo;
        }
        __syncthreads();   // h(s+1) visible
    }

    // epilogue: out[b] = h_final @ Wd + bd (h_final in hf0 registers)
    if (hf == 0) red[q * Hh + u] = h_st * Wd[u];
    __syncthreads();
    if (t < EPB) {
        float acc = bd[0];
        for (int k = 0; k < Hh; ++k) acc += red[t * Hh + k];
        out[b0 + t] = acc;
    }
}

extern "C" void kernel_launch(void* const* d_in, const int* in_sizes, int n_in,
                              void* d_out, int out_size, void* d_ws, size_t ws_size,
                              hipStream_t stream) {
    const float* x    = (const float*)d_in[0];
    const float* Wi   = (const float*)d_in[1];
    const float* Wh   = (const float*)d_in[2];
    const float* bias = (const float*)d_in[3];
    const float* Wd   = (const float*)d_in[4];
    const float* bd   = (const float*)d_in[5];
    float* out = (float*)d_out;

    lstm_mfma4<<<dim3(Bsz / EPB), dim3(NT), 0, stream>>>(x, Wi, Wh, bias, Wd, bd, out);
}

// Round 6
// 828.316 us; speedup vs baseline: 1.4348x; 1.4348x over previous
//
#include <hip/hip_runtime.h>
#include <math.h>
#include <stdint.h>

// Fused LSTM via fp16 2-term compensated MFMA, v5.
// gates = (h_hi + h_lo) @ W_hi, fp16 splits, K-interleaved: virtual K'=256
// with A'[2k]=h_hi[k], A'[2k+1]=h_lo[k], B'[2k]=B'[2k+1]=W_hi[k].
// h state is exact to 22 bits (recurrence unperturbed); W perturbed at 2^-12.
// 256 blocks x 512 threads (8 waves, 2/SIMD), ONE barrier/step (proven v3
// structure). amdgpu_waves_per_eu(2,2) raises VGPR cap to 256 -> no spills
// (v3/v4 spilled: VGPR_Count=128 vs ~210 live, WRITE_SIZE 19MB scratch).
// Real batch rows at tile rows {0,4,8,12}: acc[g][0] = own (elem q, unit u).

constexpr int Bsz = 1024;
constexpr int Ssz = 1024;
constexpr int Hh  = 128;
constexpr int NT  = 512;
constexpr int EPB = 4;

using half8 = __attribute__((ext_vector_type(8))) _Float16;
using f32x4 = __attribute__((ext_vector_type(4))) float;

__device__ __forceinline__ float sigm(float x) {
    return __builtin_amdgcn_rcpf(1.0f + __expf(-x));
}
__device__ __forceinline__ float tanh_fast(float x) {
    return 1.0f - 2.0f * __builtin_amdgcn_rcpf(1.0f + __expf(2.0f * x));
}

// Logical byte offset of k' within a 512 B A-row (fragment-contiguous):
// lane group q reading ktile kt finds its 16 B chunk at logical kt*64+q*16;
// element j of the chunk is k' = kt*32 + 16*(j>>2) + q*4 + (j&3).
__device__ __forceinline__ int kbyte(int kp) {
    return ((kp >> 5) << 6) + (((kp & 15) >> 2) << 4)
         + (((kp & 3) + ((kp >> 4) & 1) * 4) << 1);
}

__global__ __launch_bounds__(NT)
__attribute__((amdgpu_waves_per_eu(2, 2)))
void lstm_mfma5(const float* __restrict__ x,  const float* __restrict__ Wi,
                const float* __restrict__ Wh, const float* __restrict__ bias,
                const float* __restrict__ Wd, const float* __restrict__ bd,
                float* __restrict__ out)
{
    __shared__ float xs[Ssz][EPB];                      // 16 KB x transposed
    __shared__ __align__(16) uint16_t Abuf[2][16 * 256]; // 2x8 KB A' (K'=256)
    __shared__ float red[NT];                           // 2 KB epilogue

    const int t  = threadIdx.x;
    const int w  = t >> 6;                 // wave 0..7
    const int l  = t & 63;
    const int q  = l >> 4;                 // elem (C tile row 4q)
    const int cl = l & 15;
    const int b0 = blockIdx.x * EPB;
    const int u  = 16 * w + cl;            // this lane's hidden unit

    // stage x transposed (coalesced, one-time)
    for (int i = t; i < EPB * Ssz; i += NT) {
        int e = i >> 10, s = i & (Ssz - 1);
        xs[s][e] = x[(size_t)(b0 + e) * Ssz + s];
    }
    // zero A buffers (rows != {0,4,8,12} stay zero forever)
    {
        uint32_t* pa = (uint32_t*)Abuf;
        for (int i = t; i < 4096; i += NT) pa[i] = 0u;
    }

    // B fragments: W_hi fp16, 4 gates x 8 ktiles (K'=256, pairs duplicated)
    half8 Bf[4][8];
    #pragma unroll
    for (int g = 0; g < 4; ++g) {
        const int colabs = g * Hh + u;
        #pragma unroll
        for (int kt = 0; kt < 8; ++kt) {
            #pragma unroll
            for (int j = 0; j < 8; ++j) {
                int kp = kt * 32 + ((j >> 2) << 4) + q * 4 + (j & 3);
                int k  = kp >> 1;          // real k (hi/lo pair share W_hi)
                Bf[g][kt][j] = (_Float16)Wh[k * 512 + colabs];
            }
        }
    }
    float wi_g[4], b_g[4];
    #pragma unroll
    for (int g = 0; g < 4; ++g) {
        wi_g[g] = Wi[g * Hh + u];
        b_g[g]  = bias[g * Hh + u];
    }

    // A-frag read offsets (row cl; per-row phase rotation, <=2-way = free)
    int roff[8];
    #pragma unroll
    for (int kt = 0; kt < 8; ++kt)
        roff[kt] = cl * 512 + ((kt * 64 + q * 16 + cl * 16) & 511);
    const bool aload = ((cl & 3) == 0);
    // write offset: u32 (h_hi,h_lo) pair at k'=2u in row 4q
    const int woff = (q * 4) * 512 + ((kbyte(2 * u) + q * 4 * 16) & 511);

    half8 af[8];
    #pragma unroll
    for (int kt = 0; kt < 8; ++kt) af[kt] = (half8)(_Float16)0.0f;
    const f32x4 zv = (f32x4){0.f, 0.f, 0.f, 0.f};

    float cst = 0.f, h_st = 0.f;
    __syncthreads();

    for (int s = 0; s < Ssz; ++s) {
        const char* Ab = (const char*)&Abuf[s & 1][0];
        if (aload) {
            #pragma unroll
            for (int kt = 0; kt < 8; ++kt)
                af[kt] = *(const half8*)(Ab + roff[kt]);
        }
        // 8-deep chain per gate, 4 independent chains
        f32x4 ca[4];
        #pragma unroll
        for (int g = 0; g < 4; ++g)
            ca[g] = __builtin_amdgcn_mfma_f32_16x16x32_f16(af[0], Bf[g][0], zv, 0, 0, 0);
        #pragma unroll
        for (int kt = 1; kt < 8; ++kt)
            #pragma unroll
            for (int g = 0; g < 4; ++g)
                ca[g] = __builtin_amdgcn_mfma_f32_16x16x32_f16(af[kt], Bf[g][kt], ca[g], 0, 0, 0);

        const float xv = xs[s][q];
        float pi = ca[0][0] + fmaf(xv, wi_g[0], b_g[0]);
        float pf = ca[1][0] + fmaf(xv, wi_g[1], b_g[1]);
        float pg = ca[2][0] + fmaf(xv, wi_g[2], b_g[2]);
        float po = ca[3][0] + fmaf(xv, wi_g[3], b_g[3]);
        float ig = sigm(pi);
        float fg = sigm(pf);
        float gg = tanh_fast(pg);
        float og = sigm(po);
        cst  = fmaf(fg, cst, ig * gg);
        h_st = og * tanh_fast(cst);
        // fp16 hi/lo split, packed u32 (hi at lower address)
        _Float16 hh = (_Float16)h_st;
        _Float16 hl = (_Float16)(h_st - (float)hh);
        uint32_t pk = (uint32_t)__builtin_bit_cast(unsigned short, hh)
                    | ((uint32_t)__builtin_bit_cast(unsigned short, hl) << 16);
        *(uint32_t*)((char*)&Abuf[(s + 1) & 1][0] + woff) = pk;
        __syncthreads();
    }

    // epilogue: out[b] = h_final @ Wd + bd (h_final in registers)
    red[q * Hh + u] = h_st * Wd[u];
    __syncthreads();
    if (t < EPB) {
        float acc = bd[0];
        for (int k = 0; k < Hh; ++k) acc += red[t * Hh + k];
        out[b0 + t] = acc;
    }
}

extern "C" void kernel_launch(void* const* d_in, const int* in_sizes, int n_in,
                              void* d_out, int out_size, void* d_ws, size_t ws_size,
                              hipStream_t stream) {
    const float* x    = (const float*)d_in[0];
    const float* Wi   = (const float*)d_in[1];
    const float* Wh   = (const float*)d_in[2];
    const float* bias = (const float*)d_in[3];
    const float* Wd   = (const float*)d_in[4];
    const float* bd   = (const float*)d_in[5];
    float* out = (float*)d_out;

    lstm_mfma5<<<dim3(Bsz / EPB), dim3(NT), 0, stream>>>(x, Wi, Wh, bias, Wd, bd, out);
}

// Round 7
// 686.182 us; speedup vs baseline: 1.7320x; 1.2071x over previous
//
#include <hip/hip_runtime.h>
#include <math.h>
#include <stdint.h>

// Fused LSTM, v6: per-gate mixed precision fp16 MFMA.
// gates i,f,o: 1-term (h_hi @ W_hi)  - sigmoid damps the h_lo omission.
// gate  g    : 2-term ((h_hi+h_lo) @ W_hi) - tanh path integrates into c.
// h_hi/h_lo stored in SEPARATE LDS arrays (block layout) so lo-term MFMAs
// reuse the same B registers (Bf halves to 64 VGPR). 20 MFMA/wave/step.
// log2e folded into W/b (2*log2e for g-gate): activations use exp2 directly.
// 256 blocks x 512 threads (8 waves), 1 barrier/step, real rows {0,4,8,12}.

constexpr int Bsz = 1024;
constexpr int Ssz = 1024;
constexpr int Hh  = 128;
constexpr int NT  = 512;
constexpr int EPB = 4;

using half8 = __attribute__((ext_vector_type(8))) _Float16;
using f32x4 = __attribute__((ext_vector_type(4))) float;

__device__ __forceinline__ float sigm2(float p) {      // 1/(1+2^-p)
    return __builtin_amdgcn_rcpf(1.0f + exp2f(-p));
}
__device__ __forceinline__ float tanh2(float p) {      // tanh with p=2x*log2e
    return 1.0f - 2.0f * __builtin_amdgcn_rcpf(1.0f + exp2f(p));
}

// byte offset of k within a 256 B fragment-contiguous A-row (K=128 fp16):
// lane group q, ktile kt reads 16 B at logical kt*64+q*16; element j there
// is k = kt*32 + 16*(j>>2) + q*4 + (j&3).
__device__ __forceinline__ int kbyte_of_u(int k) {
    return ((k >> 5) << 6) + (((k & 15) >> 2) << 4)
         + (((k & 3) + ((k >> 4) & 1) * 4) << 1);
}

__global__ __launch_bounds__(NT)
__attribute__((amdgpu_waves_per_eu(2, 2)))
void lstm_mfma6(const float* __restrict__ x,  const float* __restrict__ Wi,
                const float* __restrict__ Wh, const float* __restrict__ bias,
                const float* __restrict__ Wd, const float* __restrict__ bd,
                float* __restrict__ out)
{
    __shared__ float xs[Ssz][EPB];                        // 16 KB x^T
    __shared__ __align__(16) uint16_t Ahi[2][16 * Hh];    // 2x4 KB h_hi fp16
    __shared__ __align__(16) uint16_t Alo[2][16 * Hh];    // 2x4 KB h_lo fp16
    __shared__ float red[NT];                             // 2 KB epilogue

    const int t  = threadIdx.x;
    const int w  = t >> 6;                 // wave 0..7
    const int l  = t & 63;
    const int q  = l >> 4;                 // elem (C tile row 4q)
    const int cl = l & 15;
    const int b0 = blockIdx.x * EPB;
    const int u  = 16 * w + cl;            // this lane's hidden unit

    const float L2E = 1.4426950408889634f;

    // stage x transposed (coalesced, one-time)
    for (int i = t; i < EPB * Ssz; i += NT) {
        int e = i >> 10, s = i & (Ssz - 1);
        xs[s][e] = x[(size_t)(b0 + e) * Ssz + s];
    }
    // zero A buffers (rows != {0,4,8,12} stay zero forever)
    {
        uint32_t* pa = (uint32_t*)Ahi;
        uint32_t* pb = (uint32_t*)Alo;
        for (int i = t; i < 2048; i += NT) { pa[i] = 0u; pb[i] = 0u; }
    }

    // B fragments: W_hi fp16 pre-scaled by log2e (2*log2e for g-gate).
    // Bf[g][kt] shared between hi and lo terms (block layout).
    half8 Bf[4][4];
    #pragma unroll
    for (int g = 0; g < 4; ++g) {
        const float sc = (g == 2) ? 2.0f * L2E : L2E;
        const int colabs = g * Hh + u;
        #pragma unroll
        for (int kt = 0; kt < 4; ++kt) {
            #pragma unroll
            for (int j = 0; j < 8; ++j) {
                int k = kt * 32 + ((j >> 2) << 4) + q * 4 + (j & 3);
                Bf[g][kt][j] = (_Float16)(Wh[k * 512 + colabs] * sc);
            }
        }
    }
    float wi_g[4], b_g[4];
    #pragma unroll
    for (int g = 0; g < 4; ++g) {
        const float sc = (g == 2) ? 2.0f * L2E : L2E;
        wi_g[g] = Wi[g * Hh + u] * sc;
        b_g[g]  = bias[g * Hh + u] * sc;
    }

    // A-frag read offsets (row cl; per-row rotation, conflict-free)
    int roff[4];
    #pragma unroll
    for (int kt = 0; kt < 4; ++kt)
        roff[kt] = cl * 256 + ((kt * 64 + q * 16 + cl * 16) & 255);
    const bool aload = ((cl & 3) == 0);
    const int woff = (q * 4) * 256 + ((kbyte_of_u(u) + q * 64) & 255);

    half8 ah[4], al[4];
    #pragma unroll
    for (int kt = 0; kt < 4; ++kt) {
        ah[kt] = (half8)(_Float16)0.0f;
        al[kt] = (half8)(_Float16)0.0f;
    }
    const f32x4 zv = (f32x4){0.f, 0.f, 0.f, 0.f};

    float cst = 0.f, h_st = 0.f;
    __syncthreads();

    for (int s = 0; s < Ssz; ++s) {
        const char* Ah = (const char*)&Ahi[s & 1][0];
        const char* Al = (const char*)&Alo[s & 1][0];
        if (aload) {
            #pragma unroll
            for (int kt = 0; kt < 4; ++kt) {
                ah[kt] = *(const half8*)(Ah + roff[kt]);
                al[kt] = *(const half8*)(Al + roff[kt]);
            }
        }
        __builtin_amdgcn_s_setprio(1);
        // i,f,o chains: 4-deep (hi term only); g chain: 8-deep (hi+lo)
        f32x4 ci, cf, co, cg;
        ci = __builtin_amdgcn_mfma_f32_16x16x32_f16(ah[0], Bf[0][0], zv, 0, 0, 0);
        cf = __builtin_amdgcn_mfma_f32_16x16x32_f16(ah[0], Bf[1][0], zv, 0, 0, 0);
        co = __builtin_amdgcn_mfma_f32_16x16x32_f16(ah[0], Bf[3][0], zv, 0, 0, 0);
        cg = __builtin_amdgcn_mfma_f32_16x16x32_f16(ah[0], Bf[2][0], zv, 0, 0, 0);
        #pragma unroll
        for (int kt = 1; kt < 4; ++kt) {
            ci = __builtin_amdgcn_mfma_f32_16x16x32_f16(ah[kt], Bf[0][kt], ci, 0, 0, 0);
            cf = __builtin_amdgcn_mfma_f32_16x16x32_f16(ah[kt], Bf[1][kt], cf, 0, 0, 0);
            co = __builtin_amdgcn_mfma_f32_16x16x32_f16(ah[kt], Bf[3][kt], co, 0, 0, 0);
            cg = __builtin_amdgcn_mfma_f32_16x16x32_f16(ah[kt], Bf[2][kt], cg, 0, 0, 0);
        }
        #pragma unroll
        for (int kt = 0; kt < 4; ++kt)
            cg = __builtin_amdgcn_mfma_f32_16x16x32_f16(al[kt], Bf[2][kt], cg, 0, 0, 0);
        __builtin_amdgcn_s_setprio(0);

        const float xv = xs[s][q];
        // i,f,o activate first (their chains retire before g's)
        float ig = sigm2(ci[0] + fmaf(xv, wi_g[0], b_g[0]));
        float fg = sigm2(cf[0] + fmaf(xv, wi_g[1], b_g[1]));
        float og = sigm2(co[0] + fmaf(xv, wi_g[3], b_g[3]));
        float gg = tanh2(cg[0] + fmaf(xv, wi_g[2], b_g[2]));
        cst  = fmaf(fg, cst, ig * gg);
        h_st = og * tanh2(cst * (2.0f * L2E));
        // fp16 hi/lo split
        _Float16 hh = (_Float16)h_st;
        _Float16 hl = (_Float16)(h_st - (float)hh);
        *(uint16_t*)((char*)&Ahi[(s + 1) & 1][0] + woff) =
            __builtin_bit_cast(unsigned short, hh);
        *(uint16_t*)((char*)&Alo[(s + 1) & 1][0] + woff) =
            __builtin_bit_cast(unsigned short, hl);
        __syncthreads();
    }

    // epilogue: out[b] = h_final @ Wd + bd (h_final in registers)
    red[q * Hh + u] = h_st * Wd[u];
    __syncthreads();
    if (t < EPB) {
        float acc = bd[0];
        for (int k = 0; k < Hh; ++k) acc += red[t * Hh + k];
        out[b0 + t] = acc;
    }
}

extern "C" void kernel_launch(void* const* d_in, const int* in_sizes, int n_in,
                              void* d_out, int out_size, void* d_ws, size_t ws_size,
                              hipStream_t stream) {
    const float* x    = (const float*)d_in[0];
    const float* Wi   = (const float*)d_in[1];
    const float* Wh   = (const float*)d_in[2];
    const float* bias = (const float*)d_in[3];
    const float* Wd   = (const float*)d_in[4];
    const float* bd   = (const float*)d_in[5];
    float* out = (float*)d_out;

    lstm_mfma6<<<dim3(Bsz / EPB), dim3(NT), 0, stream>>>(x, Wi, Wh, bias, Wd, bd, out);
}